// Round 3
// baseline (534.787 us; speedup 1.0000x reference)
//
#include <hip/hip_runtime.h>

typedef unsigned short u16;
typedef unsigned int   u32;
typedef __attribute__((ext_vector_type(8))) short short8;  // 8 bf16 (4 VGPRs)
typedef __attribute__((ext_vector_type(4))) float f32x4;

#define MFMA16(a, b, c) __builtin_amdgcn_mfma_f32_16x16x32_bf16((a), (b), (c), 0, 0, 0)

static constexpr int B_ = 8;
static constexpr int HW = 3136;   // 56*56
static constexpr int KW = 784;    // 28*28
static constexpr int NELEM = B_ * 256 * HW;  // 6422528

// ---- workspace layout (bytes). Needs ~29.5 MB of d_ws. ----
static constexpr size_t OFF_CNT = 4096;   // int: dtype-detect counter (>=64 -> f32 inputs)
static constexpr size_t OFF_W   = 8192;   // bf16 weight arena
// arena offsets in u16 units
static constexpr int AOFF_WQ = 0, AOFF_WK = 65536, AOFF_WV = 131072, AOFF_WO = 196608;
static constexpr int AOFF_WKDW = 262144, AOFF_WVDW = 264448;
static constexpr int AOFF_BKDW = 266752, AOFF_BVDW = 267008, AOFF_BQ = 267264;
static constexpr int AOFF_BK = 267520, AOFF_BV = 267776, AOFF_BO = 268032;
static constexpr size_t OFF_XT  = 557056;
static constexpr size_t SZ_XT   = (size_t)B_ * HW * 256 * 2;  // 12845056
static constexpr size_t SZ_KJ   = (size_t)B_ * KW * 256 * 2;  // 3211264
static constexpr size_t OFF_KIT = OFF_XT + SZ_XT;
static constexpr size_t OFF_VIT = OFF_KIT + SZ_KJ;
static constexpr size_t OFF_KI  = OFF_VIT + SZ_KJ;  // conv-k out, later reused for k-proj out
static constexpr size_t OFF_VI  = OFF_KI + SZ_KJ;   // conv-v out, later reused for vT
static constexpr size_t OFF_Q   = OFF_VI + SZ_KJ;
static constexpr size_t OFF_O   = OFF_XT;           // overlays xt (dead after proj_q)

__device__ __forceinline__ float bf2f(u16 u) { return __uint_as_float(((u32)u) << 16); }
__device__ __forceinline__ u16 f2bf(float f) {
  u32 u = __float_as_uint(f);
  u32 r = u + 0x7FFFu + ((u >> 16) & 1u);
  return (u16)(r >> 16);
}
__device__ __forceinline__ float bflo(u32 u) { return __uint_as_float(u << 16); }
__device__ __forceinline__ float bfhi(u32 u) { return __uint_as_float(u & 0xFFFF0000u); }
__device__ __forceinline__ u32 packbf(float a, float b) {
  u32 ua = __float_as_uint(a); ua = (ua + 0x7FFFu + ((ua >> 16) & 1u)) >> 16;
  u32 ub = __float_as_uint(b); ub = (ub + 0x7FFFu + ((ub >> 16) & 1u)) >> 16;
  return ua | (ub << 16);
}

// ---- dtype detect: low 16 bits of first 4096 words of x, decoded as bf16 ----
__global__ __launch_bounds__(256) void detect_k(const u32* __restrict__ x, int* __restrict__ cnt) {
  int c = 0;
  for (int i = threadIdx.x; i < 4096; i += 256) {
    float v = __uint_as_float(x[i] << 16);
    if (fabsf(v) > 1e4f) c++;
  }
#pragma unroll
  for (int off = 32; off > 0; off >>= 1) c += __shfl_down(c, off);
  if ((threadIdx.x & 63) == 0) atomicAdd(cnt, c);
}

// ---- canonicalize 12 weight/bias tensors into bf16 arena ----
struct CvtArgs { const void* src[12]; int dstoff[12]; int n[12]; };
__global__ __launch_bounds__(256) void cvtw_k(CvtArgs a, u16* __restrict__ arena,
                                              const int* __restrict__ cnt) {
  int t = blockIdx.y;
  int n = a.n[t];
  u16* d = arena + a.dstoff[t];
  int f32m = (*cnt >= 64);
  if (f32m) {
    const float* s = (const float*)a.src[t];
    for (int i = blockIdx.x * 256 + threadIdx.x; i < n; i += gridDim.x * 256) d[i] = f2bf(s[i]);
  } else {
    const u16* s = (const u16*)a.src[t];
    for (int i = blockIdx.x * 256 + threadIdx.x; i < n; i += gridDim.x * 256) d[i] = s[i];
  }
}

// ---- global sum / sumsq of x (single-scalar LayerNorm), dual dtype ----
__global__ __launch_bounds__(256) void reduce_k(const void* __restrict__ x, double* __restrict__ acc,
                                                const int* __restrict__ cnt) {
  int f32m = (*cnt >= 64);
  float s = 0.f, ss = 0.f;
  if (f32m) {
    const float4* xv = (const float4*)x;
    const int n4 = NELEM / 4;
    for (int i = blockIdx.x * 256 + threadIdx.x; i < n4; i += gridDim.x * 256) {
      float4 u = xv[i];
      s += u.x + u.y + u.z + u.w;
      ss += u.x * u.x + u.y * u.y + u.z * u.z + u.w * u.w;
    }
  } else {
    const uint4* xv = (const uint4*)x;
    const int n8 = NELEM / 8;
    for (int i = blockIdx.x * 256 + threadIdx.x; i < n8; i += gridDim.x * 256) {
      uint4 u = xv[i];
      u32 w[4] = {u.x, u.y, u.z, u.w};
#pragma unroll
      for (int q = 0; q < 4; q++) {
        float f0 = __uint_as_float(w[q] << 16);
        float f1 = __uint_as_float(w[q] & 0xFFFF0000u);
        s += f0 + f1;
        ss += f0 * f0 + f1 * f1;
      }
    }
  }
#pragma unroll
  for (int off = 32; off > 0; off >>= 1) {
    s += __shfl_down(s, off);
    ss += __shfl_down(ss, off);
  }
  __shared__ float as_[4], ass_[4];
  int wv = threadIdx.x >> 6;
  if ((threadIdx.x & 63) == 0) { as_[wv] = s; ass_[wv] = ss; }
  __syncthreads();
  if (threadIdx.x == 0) {
    atomicAdd(acc + 0, (double)(as_[0] + as_[1] + as_[2] + as_[3]));
    atomicAdd(acc + 1, (double)(ass_[0] + ass_[1] + ass_[2] + ass_[3]));
  }
}

// ---- mu/rstd + folded Q-projection constants ----
__global__ __launch_bounds__(256) void prep_k(const u16* __restrict__ wq, const u16* __restrict__ bq,
                                              float* __restrict__ wsf) {
  const double* acc = (const double*)wsf;
  __shared__ float sh[2];
  if (threadIdx.x == 0) {
    double N = (double)NELEM;
    double mu = acc[0] / N;
    double var = acc[1] / N - mu * mu;
    float rstd = (float)(1.0 / sqrt(var + 1e-5));
    sh[0] = (float)mu; sh[1] = rstd;
    wsf[4] = (float)mu; wsf[5] = rstd;
    wsf[6] = rstd * 0.17677669529663687f;  // rstd / sqrt(32)
  }
  __syncthreads();
  int o = threadIdx.x;
  float wsum = 0.f;
  for (int c = 0; c < 256; c++) wsum += bf2f(wq[o * 256 + c]);
  wsf[16 + o] = (bf2f(bq[o]) - sh[1] * sh[0] * wsum) * 0.17677669529663687f;
}

// ---- x [b][256][3136] -> xt [b][3136][256], dual dtype, bf16 out ----
__global__ __launch_bounds__(256) void transpose_x_k(const void* __restrict__ src, u16* __restrict__ dst,
                                                     const int* __restrict__ cnt) {
  int f32m = (*cnt >= 64);
  __shared__ u16 t[32][33];
  int b = blockIdx.z;
  int r0 = blockIdx.y * 32, c0 = blockIdx.x * 32;
  int tid = threadIdx.x, col = tid & 31;
  size_t base = (size_t)b * 256 * HW;
  if (f32m) {
    const float* s = (const float*)src + base;
#pragma unroll
    for (int i = 0; i < 4; i++) {
      int row = (tid >> 5) + i * 8;
      t[row][col] = f2bf(s[(size_t)(r0 + row) * HW + c0 + col]);
    }
  } else {
    const u16* s = (const u16*)src + base;
#pragma unroll
    for (int i = 0; i < 4; i++) {
      int row = (tid >> 5) + i * 8;
      t[row][col] = s[(size_t)(r0 + row) * HW + c0 + col];
    }
  }
  __syncthreads();
  u16* d = dst + base;
#pragma unroll
  for (int i = 0; i < 4; i++) {
    int row = (tid >> 5) + i * 8;  // indexes HW-dim in dst
    d[(size_t)(c0 + row) * 256 + r0 + col] = t[col][row];
  }
}

// ---- bf16 per-batch [256][784] -> [784][256] transpose for BOTH conv outputs ----
__global__ __launch_bounds__(256) void transpose_kv_k(const u16* __restrict__ s1, u16* __restrict__ d1,
                                                      const u16* __restrict__ s2, u16* __restrict__ d2) {
  __shared__ u16 t[32][33];
  int which = blockIdx.z >> 3;
  int b = blockIdx.z & 7;
  const u16* src = which ? s2 : s1;
  u16* dst = which ? d2 : d1;
  int r0 = blockIdx.y * 32, c0 = blockIdx.x * 32;
  const u16* s = src + (size_t)b * 256 * KW;
  u16* d = dst + (size_t)b * 256 * KW;
  int tid = threadIdx.x, col = tid & 31;
#pragma unroll
  for (int i = 0; i < 4; i++) {
    int row = (tid >> 5) + i * 8;
    if (c0 + col < KW) t[row][col] = s[(size_t)(r0 + row) * KW + c0 + col];
  }
  __syncthreads();
#pragma unroll
  for (int i = 0; i < 4; i++) {
    int row = (tid >> 5) + i * 8;
    if (c0 + row < KW) d[(size_t)(c0 + row) * 256 + r0 + col] = t[col][row];
  }
}

// ---- depthwise 3x3 stride-2 conv, dual-dtype x, arena weights, bf16 out ----
__global__ __launch_bounds__(256) void dwconv_k(const void* __restrict__ x,
                                                const u16* __restrict__ arena,
                                                u16* __restrict__ ki, u16* __restrict__ vi,
                                                const int* __restrict__ cnt) {
  int f32m = (*cnt >= 64);
  int b = blockIdx.x >> 8;
  int c = blockIdx.x & 255;
  float wkf[9], wvf[9];
#pragma unroll
  for (int t = 0; t < 9; t++) {
    wkf[t] = bf2f(arena[AOFF_WKDW + c * 9 + t]);
    wvf[t] = bf2f(arena[AOFF_WVDW + c * 9 + t]);
  }
  float kb = bf2f(arena[AOFF_BKDW + c]), vb = bf2f(arena[AOFF_BVDW + c]);
  size_t xbase = (size_t)(b * 256 + c) * HW;
  auto body = [&](auto LDX) {
    for (int j = threadIdx.x; j < KW; j += 256) {
      int oi = j / 28, oj = j % 28;
      float ka = kb, va = vb;
#pragma unroll
      for (int di = 0; di < 3; di++) {
        int ii = 2 * oi - 1 + di;
        if ((unsigned)ii >= 56u) continue;
#pragma unroll
        for (int dj = 0; dj < 3; dj++) {
          int ij = 2 * oj - 1 + dj;
          if ((unsigned)ij >= 56u) continue;
          float xv = LDX(ii * 56 + ij);
          ka += xv * wkf[di * 3 + dj];
          va += xv * wvf[di * 3 + dj];
        }
      }
      ki[(size_t)(b * 256 + c) * KW + j] = f2bf(ka);
      vi[(size_t)(b * 256 + c) * KW + j] = f2bf(va);
    }
  };
  if (f32m) {
    const float* xp = (const float*)x + xbase;
    body([&](int i) { return xp[i]; });
  } else {
    const u16* xp = (const u16*)x + xbase;
    body([&](int i) { return bf2f(xp[i]); });
  }
}

// ---- Q projection ----
__global__ __launch_bounds__(256) void proj_q_k(const u16* __restrict__ xt, const u16* __restrict__ Wq,
                                                const float* __restrict__ wsf, u16* __restrict__ q) {
  int lane = threadIdx.x & 63, wave = threadIdx.x >> 6;
  int l15 = lane & 15, quad = lane >> 4;
  int b = blockIdx.x / 49, pb = blockIdx.x % 49;
  int p0 = pb * 64 + wave * 16;
  const u16* arow = xt + ((size_t)(b * HW) + p0 + l15) * 256 + quad * 8;
  short8 af[8];
#pragma unroll
  for (int ks = 0; ks < 8; ks++) af[ks] = *(const short8*)(arow + ks * 32);
  float alpha = wsf[6];
  const float* beta = wsf + 16;
  for (int ot = 0; ot < 16; ot++) {
    const u16* brow = Wq + (size_t)(ot * 16 + l15) * 256 + quad * 8;
    f32x4 acc = {0.f, 0.f, 0.f, 0.f};
#pragma unroll
    for (int ks = 0; ks < 8; ks++) acc = MFMA16(af[ks], *(const short8*)(brow + ks * 32), acc);
    int o = ot * 16 + l15;
    float bet = beta[o];
    size_t base = ((size_t)(b * HW) + p0 + quad * 4) * 256 + o;
#pragma unroll
    for (int r = 0; r < 4; r++) q[base + (size_t)r * 256] = f2bf(alpha * acc[r] + bet);
  }
}

// ---- K projection ----
__global__ __launch_bounds__(256) void proj_k_k(const u16* __restrict__ kit, const u16* __restrict__ Wk,
                                                const u16* __restrict__ bk, u16* __restrict__ kout) {
  int lane = threadIdx.x & 63, wave = threadIdx.x >> 6;
  int l15 = lane & 15, quad = lane >> 4;
  int b = blockIdx.x / 13, jb = blockIdx.x % 13;
  int p0 = jb * 64 + wave * 16;
  if (p0 >= KW) return;
  const u16* arow = kit + ((size_t)(b * KW) + p0 + l15) * 256 + quad * 8;
  short8 af[8];
#pragma unroll
  for (int ks = 0; ks < 8; ks++) af[ks] = *(const short8*)(arow + ks * 32);
  for (int ot = 0; ot < 16; ot++) {
    const u16* brow = Wk + (size_t)(ot * 16 + l15) * 256 + quad * 8;
    f32x4 acc = {0.f, 0.f, 0.f, 0.f};
#pragma unroll
    for (int ks = 0; ks < 8; ks++) acc = MFMA16(af[ks], *(const short8*)(brow + ks * 32), acc);
    int o = ot * 16 + l15;
    float bias = bf2f(bk[o]);
    size_t base = ((size_t)(b * KW) + p0 + quad * 4) * 256 + o;
#pragma unroll
    for (int r = 0; r < 4; r++) kout[base + (size_t)r * 256] = f2bf(acc[r] + bias);
  }
}

// ---- V projection, transposed output vT[b][o][j] ----
__global__ __launch_bounds__(256) void proj_v_k(const u16* __restrict__ Wv, const u16* __restrict__ vit,
                                                const u16* __restrict__ bv, u16* __restrict__ vT) {
  int lane = threadIdx.x & 63, wave = threadIdx.x >> 6;
  int l15 = lane & 15, quad = lane >> 4;
  int b = blockIdx.x >> 4;
  int ob = (blockIdx.x >> 2) & 3;
  int js = blockIdx.x & 3;
  int o0 = ob * 64 + wave * 16;
  const u16* arow = Wv + (size_t)(o0 + l15) * 256 + quad * 8;
  short8 af[8];
#pragma unroll
  for (int ks = 0; ks < 8; ks++) af[ks] = *(const short8*)(arow + ks * 32);
  int jt0 = js * 13;
  int jt1 = (jt0 + 13 < 49) ? jt0 + 13 : 49;
  for (int jt = jt0; jt < jt1; jt++) {
    const u16* brow = vit + ((size_t)(b * KW) + jt * 16 + l15) * 256 + quad * 8;
    f32x4 acc = {0.f, 0.f, 0.f, 0.f};
#pragma unroll
    for (int ks = 0; ks < 8; ks++) acc = MFMA16(af[ks], *(const short8*)(brow + ks * 32), acc);
#pragma unroll
    for (int r = 0; r < 4; r++) {
      int o = o0 + quad * 4 + r;
      vT[((size_t)(b * 256) + o) * KW + jt * 16 + l15] = f2bf(acc[r] + bf2f(bv[o]));
    }
  }
}

// ---- fused attention: 256-thr block = 4 waves = 4 batches of one (pt, h, half) ----
// Grid: blockIdx.x = pt*16 + h*2 + half; wave w handles b = half*4 + w.
// Bias tile (16 rows x 784, no b-dependence) staged once per block into LDS as bf16.
static constexpr int BSTRIDE = 788;  // u16 row stride; 1576 B: 8B-aligned, bank offset 10
__global__ __launch_bounds__(256) void attn_k(const u16* __restrict__ q, const u16* __restrict__ k,
                                              const u16* __restrict__ vT, const void* __restrict__ Bb,
                                              u16* __restrict__ Ob, const int* __restrict__ cnt) {
  int f32m = (*cnt >= 64);
  int tid = threadIdx.x;
  int lane = tid & 63, wave = tid >> 6;
  int l15 = lane & 15, quad = lane >> 4;
  int bid = blockIdx.x;
  int pt = bid >> 4;
  int h = (bid >> 1) & 7;
  int half = bid & 1;
  int b = half * 4 + wave;
  int p0 = pt * 16;
  __shared__ __align__(16) u16 bls[16 * BSTRIDE];   // bias tile bf16
  __shared__ __align__(16) u16 Pch[4][16][40];      // per-wave P chunk, row stride 80 B

  // cooperative bias tile load: rows p0..p0+15, cols 0..783 (3136 4-col chunks)
  {
    size_t boff = ((size_t)(h * HW) + p0) * KW;
    if (f32m) {
      const float* bbf = (const float*)Bb + boff;
#pragma unroll
      for (int it = 0; it < 13; it++) {
        int chunk = it * 256 + tid;
        if (chunk < 3136) {
          int row = chunk / 196, c4 = chunk - row * 196;
          float4 v = *(const float4*)(bbf + (size_t)row * KW + c4 * 4);
          uint2 p;
          p.x = packbf(v.x, v.y);
          p.y = packbf(v.z, v.w);
          *(uint2*)&bls[row * BSTRIDE + c4 * 4] = p;
        }
      }
    } else {
      const u16* bbb = (const u16*)Bb + boff;
#pragma unroll
      for (int it = 0; it < 13; it++) {
        int chunk = it * 256 + tid;
        if (chunk < 3136) {
          int row = chunk / 196, c4 = chunk - row * 196;
          *(uint2*)&bls[row * BSTRIDE + c4 * 4] = *(const uint2*)(bbb + (size_t)row * KW + c4 * 4);
        }
      }
    }
  }
  __syncthreads();

  const u16* qp = q + ((size_t)(b * HW) + p0 + l15) * 256 + h * 32 + quad * 8;
  short8 af = *(const short8*)qp;
  const u16* kb = k + (size_t)b * KW * 256 + h * 32 + quad * 8;

  // scores, bf16-packed: sp[jt][0] = rows(quad*4+0,+1), sp[jt][1] = rows(+2,+3); col = jt*16+l15
  u32 sp[49][2];
#pragma unroll
  for (int jt = 0; jt < 49; jt++) {
    short8 bfr = *(const short8*)(kb + (size_t)(jt * 16 + l15) * 256);
    f32x4 acc = {0.f, 0.f, 0.f, 0.f};
    acc = MFMA16(af, bfr, acc);
    int col = jt * 16 + l15;
    float v0 = acc[0] + bf2f(bls[(quad * 4 + 0) * BSTRIDE + col]);
    float v1 = acc[1] + bf2f(bls[(quad * 4 + 1) * BSTRIDE + col]);
    float v2 = acc[2] + bf2f(bls[(quad * 4 + 2) * BSTRIDE + col]);
    float v3 = acc[3] + bf2f(bls[(quad * 4 + 3) * BSTRIDE + col]);
    sp[jt][0] = packbf(v0, v1);
    sp[jt][1] = packbf(v2, v3);
  }

  float m[4] = {-1e30f, -1e30f, -1e30f, -1e30f};
#pragma unroll
  for (int jt = 0; jt < 49; jt++) {
    m[0] = fmaxf(m[0], bflo(sp[jt][0])); m[1] = fmaxf(m[1], bfhi(sp[jt][0]));
    m[2] = fmaxf(m[2], bflo(sp[jt][1])); m[3] = fmaxf(m[3], bfhi(sp[jt][1]));
  }
#pragma unroll
  for (int off = 1; off < 16; off <<= 1)
#pragma unroll
    for (int r = 0; r < 4; r++) m[r] = fmaxf(m[r], __shfl_xor(m[r], off));
  float l[4] = {0.f, 0.f, 0.f, 0.f};
#pragma unroll
  for (int jt = 0; jt < 49; jt++) {
    float e0 = __expf(bflo(sp[jt][0]) - m[0]);
    float e1 = __expf(bfhi(sp[jt][0]) - m[1]);
    float e2 = __expf(bflo(sp[jt][1]) - m[2]);
    float e3 = __expf(bfhi(sp[jt][1]) - m[3]);
    l[0] += e0; l[1] += e1; l[2] += e2; l[3] += e3;
    sp[jt][0] = packbf(e0, e1);
    sp[jt][1] = packbf(e2, e3);
  }
#pragma unroll
  for (int off = 1; off < 16; off <<= 1)
#pragma unroll
    for (int r = 0; r < 4; r++) l[r] += __shfl_xor(l[r], off);
  float inv[4];
#pragma unroll
  for (int r = 0; r < 4; r++) inv[r] = 1.f / l[r];

  // PV: 25 chunks of 32 j; P goes D-layout -> LDS -> A-layout
  f32x4 oa = {0.f, 0.f, 0.f, 0.f}, obb = {0.f, 0.f, 0.f, 0.f};
  const u16* vb = vT + ((size_t)(b * 256) + h * 32) * KW;
#pragma unroll
  for (int ch = 0; ch < 25; ch++) {
#pragma unroll
    for (int hf = 0; hf < 2; hf++) {
      int jt = ch * 2 + hf;
      u32 p0k = 0, p1k = 0;
      if (jt < 49) { p0k = sp[jt][0]; p1k = sp[jt][1]; }
      int col = hf * 16 + l15;
      Pch[wave][quad * 4 + 0][col] = (u16)(p0k & 0xFFFFu);
      Pch[wave][quad * 4 + 1][col] = (u16)(p0k >> 16);
      Pch[wave][quad * 4 + 2][col] = (u16)(p1k & 0xFFFFu);
      Pch[wave][quad * 4 + 3][col] = (u16)(p1k >> 16);
    }
    __syncthreads();
    short8 pf = *(const short8*)(&Pch[wave][l15][quad * 8]);
    int jo = ch * 32 + quad * 8;
    if (jo > 776) jo = 776;  // clamp; those B rows only meet P==0 (j>=784 pad)
    short8 v0 = *(const short8*)(vb + (size_t)l15 * KW + jo);
    short8 v1 = *(const short8*)(vb + (size_t)(16 + l15) * KW + jo);
    oa  = MFMA16(pf, v0, oa);
    obb = MFMA16(pf, v1, obb);
    __syncthreads();
  }
  size_t obase = ((size_t)(b * HW) + p0 + quad * 4) * 256 + h * 32 + l15;
#pragma unroll
  for (int r = 0; r < 4; r++) {
    Ob[obase + (size_t)r * 256]      = f2bf(oa[r] * inv[r]);
    Ob[obase + (size_t)r * 256 + 16] = f2bf(obb[r] * inv[r]);
  }
}

// ---- O projection + .view-quirk residual; dual-dtype x read and out write ----
__global__ __launch_bounds__(256) void proj_o_k(const u16* __restrict__ Ob, const u16* __restrict__ Wo,
                                                const u16* __restrict__ bo, const void* __restrict__ x,
                                                void* __restrict__ out, const int* __restrict__ cnt) {
  int f32m = (*cnt >= 64);
  int lane = threadIdx.x & 63, wave = threadIdx.x >> 6;
  int l15 = lane & 15, quad = lane >> 4;
  int b = blockIdx.x / 49, pb = blockIdx.x % 49;
  int p0 = pb * 64 + wave * 16;
  const u16* arow = Ob + ((size_t)(b * HW) + p0 + l15) * 256 + quad * 8;
  short8 af[8];
#pragma unroll
  for (int ks = 0; ks < 8; ks++) af[ks] = *(const short8*)(arow + ks * 32);
  for (int ot = 0; ot < 16; ot++) {
    const u16* brow = Wo + (size_t)(ot * 16 + l15) * 256 + quad * 8;
    f32x4 acc = {0.f, 0.f, 0.f, 0.f};
#pragma unroll
    for (int ks = 0; ks < 8; ks++) acc = MFMA16(af[ks], *(const short8*)(brow + ks * 32), acc);
    int o = ot * 16 + l15;
    float bias = bf2f(bo[o]);
    if (f32m) {
      const float* xf = (const float*)x;
      float* of = (float*)out;
#pragma unroll
      for (int r = 0; r < 4; r++) {
        size_t idx = ((size_t)(b * HW) + p0 + quad * 4 + r) * 256 + o;
        of[idx] = acc[r] + bias + xf[idx];
      }
    } else {
      const u16* xb = (const u16*)x;
      u16* ob_ = (u16*)out;
#pragma unroll
      for (int r = 0; r < 4; r++) {
        size_t idx = ((size_t)(b * HW) + p0 + quad * 4 + r) * 256 + o;
        ob_[idx] = f2bf(acc[r] + bias + bf2f(xb[idx]));
      }
    }
  }
}

extern "C" void kernel_launch(void* const* d_in, const int* in_sizes, int n_in,
                              void* d_out, int out_size, void* d_ws, size_t ws_size,
                              hipStream_t stream) {
  (void)in_sizes; (void)n_in; (void)out_size; (void)ws_size;
  const void* x = d_in[0];
  char* ws = (char*)d_ws;
  int* cnt = (int*)(ws + OFF_CNT);
  u16* arena = (u16*)(ws + OFF_W);
  u16* xt  = (u16*)(ws + OFF_XT);
  u16* kit = (u16*)(ws + OFF_KIT);
  u16* vit = (u16*)(ws + OFF_VIT);
  u16* ki  = (u16*)(ws + OFF_KI);   // then k-proj output
  u16* vi  = (u16*)(ws + OFF_VI);   // then vT
  u16* qb  = (u16*)(ws + OFF_Q);
  u16* Obuf = (u16*)(ws + OFF_O);   // overlays xt

  CvtArgs a;
  const int srcidx[12] = {5, 7, 9, 11, 1, 3, 2, 4, 6, 8, 10, 12};
  const int dofs[12] = {AOFF_WQ, AOFF_WK, AOFF_WV, AOFF_WO, AOFF_WKDW, AOFF_WVDW,
                        AOFF_BKDW, AOFF_BVDW, AOFF_BQ, AOFF_BK, AOFF_BV, AOFF_BO};
  const int ns[12] = {65536, 65536, 65536, 65536, 2304, 2304, 256, 256, 256, 256, 256, 256};
  for (int i = 0; i < 12; i++) { a.src[i] = d_in[srcidx[i]]; a.dstoff[i] = dofs[i]; a.n[i] = ns[i]; }

  hipMemsetAsync(d_ws, 0, 8192, stream);  // zero acc + detect counter
  detect_k<<<1, 256, 0, stream>>>((const u32*)x, cnt);
  cvtw_k<<<dim3(32, 12), 256, 0, stream>>>(a, arena, cnt);
  reduce_k<<<1024, 256, 0, stream>>>(x, (double*)d_ws, cnt);
  prep_k<<<1, 256, 0, stream>>>(arena + AOFF_WQ, arena + AOFF_BQ, (float*)d_ws);
  transpose_x_k<<<dim3(98, 8, 8), 256, 0, stream>>>(x, xt, cnt);
  dwconv_k<<<2048, 256, 0, stream>>>(x, arena, ki, vi, cnt);
  transpose_kv_k<<<dim3(25, 8, 16), 256, 0, stream>>>(ki, kit, vi, vit);
  proj_k_k<<<104, 256, 0, stream>>>(kit, arena + AOFF_WK, arena + AOFF_BK, ki);
  proj_v_k<<<128, 256, 0, stream>>>(arena + AOFF_WV, vit, arena + AOFF_BV, vi);
  proj_q_k<<<392, 256, 0, stream>>>(xt, arena + AOFF_WQ, (const float*)d_ws, qb);
  attn_k<<<3136, 256, 0, stream>>>(qb, ki, vi, d_in[13], Obuf, cnt);
  proj_o_k<<<392, 256, 0, stream>>>(Obuf, arena + AOFF_WO, arena + AOFF_BO, x, d_out, cnt);
}

// Round 4
// 531.702 us; speedup vs baseline: 1.0058x; 1.0058x over previous
//
#include <hip/hip_runtime.h>

typedef unsigned short u16;
typedef unsigned int   u32;
typedef __attribute__((ext_vector_type(8))) short short8;  // 8 bf16 (4 VGPRs)
typedef __attribute__((ext_vector_type(4))) float f32x4;

#define MFMA16(a, b, c) __builtin_amdgcn_mfma_f32_16x16x32_bf16((a), (b), (c), 0, 0, 0)

static constexpr int B_ = 8;
static constexpr int HW = 3136;   // 56*56
static constexpr int KW = 784;    // 28*28
static constexpr int NELEM = B_ * 256 * HW;  // 6422528

// ---- workspace layout (bytes). Needs ~29.5 MB of d_ws. ----
static constexpr size_t OFF_CNT = 4096;   // int: dtype-detect counter (>=64 -> f32 inputs)
static constexpr size_t OFF_W   = 8192;   // bf16 weight arena
// arena offsets in u16 units
static constexpr int AOFF_WQ = 0, AOFF_WK = 65536, AOFF_WV = 131072, AOFF_WO = 196608;
static constexpr int AOFF_WKDW = 262144, AOFF_WVDW = 264448;
static constexpr int AOFF_BKDW = 266752, AOFF_BVDW = 267008, AOFF_BQ = 267264;
static constexpr int AOFF_BK = 267520, AOFF_BV = 267776, AOFF_BO = 268032;
static constexpr size_t OFF_XT  = 557056;
static constexpr size_t SZ_XT   = (size_t)B_ * HW * 256 * 2;  // 12845056
static constexpr size_t SZ_KJ   = (size_t)B_ * KW * 256 * 2;  // 3211264
static constexpr size_t OFF_KIT = OFF_XT + SZ_XT;
static constexpr size_t OFF_VIT = OFF_KIT + SZ_KJ;
static constexpr size_t OFF_KI  = OFF_VIT + SZ_KJ;  // conv-k out, later reused for k-proj out
static constexpr size_t OFF_VI  = OFF_KI + SZ_KJ;   // conv-v out, later reused for vT
static constexpr size_t OFF_Q   = OFF_VI + SZ_KJ;
static constexpr size_t OFF_O   = OFF_XT;           // overlays xt (dead after proj_q)

__device__ __forceinline__ float bf2f(u16 u) { return __uint_as_float(((u32)u) << 16); }
__device__ __forceinline__ u16 f2bf(float f) {
  u32 u = __float_as_uint(f);
  u32 r = u + 0x7FFFu + ((u >> 16) & 1u);
  return (u16)(r >> 16);
}
__device__ __forceinline__ float bflo(u32 u) { return __uint_as_float(u << 16); }
__device__ __forceinline__ float bfhi(u32 u) { return __uint_as_float(u & 0xFFFF0000u); }
__device__ __forceinline__ u32 packbf(float a, float b) {
  u32 ua = __float_as_uint(a); ua = (ua + 0x7FFFu + ((ua >> 16) & 1u)) >> 16;
  u32 ub = __float_as_uint(b); ub = (ub + 0x7FFFu + ((ub >> 16) & 1u)) >> 16;
  return ua | (ub << 16);
}

// ---- dtype detect ----
__global__ __launch_bounds__(256) void detect_k(const u32* __restrict__ x, int* __restrict__ cnt) {
  int c = 0;
  for (int i = threadIdx.x; i < 4096; i += 256) {
    float v = __uint_as_float(x[i] << 16);
    if (fabsf(v) > 1e4f) c++;
  }
#pragma unroll
  for (int off = 32; off > 0; off >>= 1) c += __shfl_down(c, off);
  if ((threadIdx.x & 63) == 0) atomicAdd(cnt, c);
}

// ---- canonicalize 12 weight/bias tensors into bf16 arena ----
struct CvtArgs { const void* src[12]; int dstoff[12]; int n[12]; };
__global__ __launch_bounds__(256) void cvtw_k(CvtArgs a, u16* __restrict__ arena,
                                              const int* __restrict__ cnt) {
  int t = blockIdx.y;
  int n = a.n[t];
  u16* d = arena + a.dstoff[t];
  int f32m = (*cnt >= 64);
  if (f32m) {
    const float* s = (const float*)a.src[t];
    for (int i = blockIdx.x * 256 + threadIdx.x; i < n; i += gridDim.x * 256) d[i] = f2bf(s[i]);
  } else {
    const u16* s = (const u16*)a.src[t];
    for (int i = blockIdx.x * 256 + threadIdx.x; i < n; i += gridDim.x * 256) d[i] = s[i];
  }
}

// ---- global sum / sumsq of x, dual dtype ----
__global__ __launch_bounds__(256) void reduce_k(const void* __restrict__ x, double* __restrict__ acc,
                                                const int* __restrict__ cnt) {
  int f32m = (*cnt >= 64);
  float s = 0.f, ss = 0.f;
  if (f32m) {
    const float4* xv = (const float4*)x;
    const int n4 = NELEM / 4;
    for (int i = blockIdx.x * 256 + threadIdx.x; i < n4; i += gridDim.x * 256) {
      float4 u = xv[i];
      s += u.x + u.y + u.z + u.w;
      ss += u.x * u.x + u.y * u.y + u.z * u.z + u.w * u.w;
    }
  } else {
    const uint4* xv = (const uint4*)x;
    const int n8 = NELEM / 8;
    for (int i = blockIdx.x * 256 + threadIdx.x; i < n8; i += gridDim.x * 256) {
      uint4 u = xv[i];
      u32 w[4] = {u.x, u.y, u.z, u.w};
#pragma unroll
      for (int q = 0; q < 4; q++) {
        float f0 = __uint_as_float(w[q] << 16);
        float f1 = __uint_as_float(w[q] & 0xFFFF0000u);
        s += f0 + f1;
        ss += f0 * f0 + f1 * f1;
      }
    }
  }
#pragma unroll
  for (int off = 32; off > 0; off >>= 1) {
    s += __shfl_down(s, off);
    ss += __shfl_down(ss, off);
  }
  __shared__ float as_[4], ass_[4];
  int wv = threadIdx.x >> 6;
  if ((threadIdx.x & 63) == 0) { as_[wv] = s; ass_[wv] = ss; }
  __syncthreads();
  if (threadIdx.x == 0) {
    atomicAdd(acc + 0, (double)(as_[0] + as_[1] + as_[2] + as_[3]));
    atomicAdd(acc + 1, (double)(ass_[0] + ass_[1] + ass_[2] + ass_[3]));
  }
}

// ---- mu/rstd + folded Q-projection constants ----
__global__ __launch_bounds__(256) void prep_k(const u16* __restrict__ wq, const u16* __restrict__ bq,
                                              float* __restrict__ wsf) {
  const double* acc = (const double*)wsf;
  __shared__ float sh[2];
  if (threadIdx.x == 0) {
    double N = (double)NELEM;
    double mu = acc[0] / N;
    double var = acc[1] / N - mu * mu;
    float rstd = (float)(1.0 / sqrt(var + 1e-5));
    sh[0] = (float)mu; sh[1] = rstd;
    wsf[4] = (float)mu; wsf[5] = rstd;
    wsf[6] = rstd * 0.17677669529663687f;  // rstd / sqrt(32)
  }
  __syncthreads();
  int o = threadIdx.x;
  float wsum = 0.f;
  for (int c = 0; c < 256; c++) wsum += bf2f(wq[o * 256 + c]);
  wsf[16 + o] = (bf2f(bq[o]) - sh[1] * sh[0] * wsum) * 0.17677669529663687f;
}

// ---- x [b][256][3136] -> xt [b][3136][256], dual dtype, bf16 out ----
__global__ __launch_bounds__(256) void transpose_x_k(const void* __restrict__ src, u16* __restrict__ dst,
                                                     const int* __restrict__ cnt) {
  int f32m = (*cnt >= 64);
  __shared__ u16 t[32][33];
  int b = blockIdx.z;
  int r0 = blockIdx.y * 32, c0 = blockIdx.x * 32;
  int tid = threadIdx.x, col = tid & 31;
  size_t base = (size_t)b * 256 * HW;
  if (f32m) {
    const float* s = (const float*)src + base;
#pragma unroll
    for (int i = 0; i < 4; i++) {
      int row = (tid >> 5) + i * 8;
      t[row][col] = f2bf(s[(size_t)(r0 + row) * HW + c0 + col]);
    }
  } else {
    const u16* s = (const u16*)src + base;
#pragma unroll
    for (int i = 0; i < 4; i++) {
      int row = (tid >> 5) + i * 8;
      t[row][col] = s[(size_t)(r0 + row) * HW + c0 + col];
    }
  }
  __syncthreads();
  u16* d = dst + base;
#pragma unroll
  for (int i = 0; i < 4; i++) {
    int row = (tid >> 5) + i * 8;
    d[(size_t)(c0 + row) * 256 + r0 + col] = t[col][row];
  }
}

// ---- bf16 per-batch [256][784] -> [784][256] transpose for BOTH conv outputs ----
__global__ __launch_bounds__(256) void transpose_kv_k(const u16* __restrict__ s1, u16* __restrict__ d1,
                                                      const u16* __restrict__ s2, u16* __restrict__ d2) {
  __shared__ u16 t[32][33];
  int which = blockIdx.z >> 3;
  int b = blockIdx.z & 7;
  const u16* src = which ? s2 : s1;
  u16* dst = which ? d2 : d1;
  int r0 = blockIdx.y * 32, c0 = blockIdx.x * 32;
  const u16* s = src + (size_t)b * 256 * KW;
  u16* d = dst + (size_t)b * 256 * KW;
  int tid = threadIdx.x, col = tid & 31;
#pragma unroll
  for (int i = 0; i < 4; i++) {
    int row = (tid >> 5) + i * 8;
    if (c0 + col < KW) t[row][col] = s[(size_t)(r0 + row) * KW + c0 + col];
  }
  __syncthreads();
#pragma unroll
  for (int i = 0; i < 4; i++) {
    int row = (tid >> 5) + i * 8;
    if (c0 + row < KW) d[(size_t)(c0 + row) * 256 + r0 + col] = t[col][row];
  }
}

// ---- depthwise 3x3 stride-2 conv ----
__global__ __launch_bounds__(256) void dwconv_k(const void* __restrict__ x,
                                                const u16* __restrict__ arena,
                                                u16* __restrict__ ki, u16* __restrict__ vi,
                                                const int* __restrict__ cnt) {
  int f32m = (*cnt >= 64);
  int b = blockIdx.x >> 8;
  int c = blockIdx.x & 255;
  float wkf[9], wvf[9];
#pragma unroll
  for (int t = 0; t < 9; t++) {
    wkf[t] = bf2f(arena[AOFF_WKDW + c * 9 + t]);
    wvf[t] = bf2f(arena[AOFF_WVDW + c * 9 + t]);
  }
  float kb = bf2f(arena[AOFF_BKDW + c]), vb = bf2f(arena[AOFF_BVDW + c]);
  size_t xbase = (size_t)(b * 256 + c) * HW;
  auto body = [&](auto LDX) {
    for (int j = threadIdx.x; j < KW; j += 256) {
      int oi = j / 28, oj = j % 28;
      float ka = kb, va = vb;
#pragma unroll
      for (int di = 0; di < 3; di++) {
        int ii = 2 * oi - 1 + di;
        if ((unsigned)ii >= 56u) continue;
#pragma unroll
        for (int dj = 0; dj < 3; dj++) {
          int ij = 2 * oj - 1 + dj;
          if ((unsigned)ij >= 56u) continue;
          float xv = LDX(ii * 56 + ij);
          ka += xv * wkf[di * 3 + dj];
          va += xv * wvf[di * 3 + dj];
        }
      }
      ki[(size_t)(b * 256 + c) * KW + j] = f2bf(ka);
      vi[(size_t)(b * 256 + c) * KW + j] = f2bf(va);
    }
  };
  if (f32m) {
    const float* xp = (const float*)x + xbase;
    body([&](int i) { return xp[i]; });
  } else {
    const u16* xp = (const u16*)x + xbase;
    body([&](int i) { return bf2f(xp[i]); });
  }
}

// ---- generic LDS-staged projection: out[b][p][o] = act[b][p][:]·W[o][:] + epilogue ----
// MODE 0 = q (alpha*acc+beta), 1 = k (acc+bias), 2 = o (acc+bias+x residual, dual out)
// grid: 224 blocks = 8 b x 7 qc x 4 og; block stages W rows og*64..+63 in LDS.
template<int MODE>
__global__ __launch_bounds__(256, 4) void proj2_k(const u16* __restrict__ act, const u16* __restrict__ Wt,
                                                  const float* __restrict__ wsf, const u16* __restrict__ bias,
                                                  const void* __restrict__ x, void* __restrict__ outp,
                                                  const int* __restrict__ cnt, int R, int tpb) {
  __shared__ __align__(16) u16 Wl[64 * 264];
  int tid = threadIdx.x, lane = tid & 63, wave = tid >> 6;
  int l15 = lane & 15, quad = lane >> 4;
  int og = blockIdx.x & 3;
  int tmp = blockIdx.x >> 2;
  int qc = tmp % 7, b = tmp / 7;
  {
    int row = tid >> 2, cb = (tid & 3) * 64;
    const u16* wsrc = Wt + (size_t)(og * 64 + row) * 256 + cb;
#pragma unroll
    for (int i = 0; i < 8; i++)
      *(short8*)&Wl[row * 264 + cb + i * 8] = *(const short8*)(wsrc + i * 8);
  }
  __syncthreads();
  int f32m = (MODE == 2) ? (*cnt >= 64) : 0;
  float alpha = (MODE == 0) ? wsf[6] : 0.f;
  for (int tt = wave; tt < tpb; tt += 4) {
    int p0 = (qc * tpb + tt) * 16;
    const u16* arow = act + ((size_t)b * R + p0 + l15) * 256 + quad * 8;
    short8 afr[8];
#pragma unroll
    for (int ks = 0; ks < 8; ks++) afr[ks] = *(const short8*)(arow + ks * 32);
#pragma unroll
    for (int ot = 0; ot < 4; ot++) {
      f32x4 acc = {0.f, 0.f, 0.f, 0.f};
#pragma unroll
      for (int ks = 0; ks < 8; ks++) {
        short8 bfr = *(const short8*)&Wl[(ot * 16 + l15) * 264 + ks * 32 + quad * 8];
        acc = MFMA16(afr[ks], bfr, acc);
      }
      int o = og * 64 + ot * 16 + l15;
      if (MODE == 0) {
        float bet = wsf[16 + o];
        u16* q = (u16*)outp;
#pragma unroll
        for (int r = 0; r < 4; r++)
          q[((size_t)b * R + p0 + quad * 4 + r) * 256 + o] = f2bf(alpha * acc[r] + bet);
      } else if (MODE == 1) {
        float bi = bf2f(bias[o]);
        u16* ko = (u16*)outp;
#pragma unroll
        for (int r = 0; r < 4; r++)
          ko[((size_t)b * R + p0 + quad * 4 + r) * 256 + o] = f2bf(acc[r] + bi);
      } else {
        float bi = bf2f(bias[o]);
        if (f32m) {
          const float* xf = (const float*)x;
          float* of = (float*)outp;
#pragma unroll
          for (int r = 0; r < 4; r++) {
            size_t idx = ((size_t)b * R + p0 + quad * 4 + r) * 256 + o;
            of[idx] = acc[r] + bi + xf[idx];
          }
        } else {
          const u16* xb = (const u16*)x;
          u16* ob_ = (u16*)outp;
#pragma unroll
          for (int r = 0; r < 4; r++) {
            size_t idx = ((size_t)b * R + p0 + quad * 4 + r) * 256 + o;
            ob_[idx] = f2bf(acc[r] + bi + bf2f(xb[idx]));
          }
        }
      }
    }
  }
}

// ---- V projection, transposed output vT[b][o][j] ----
__global__ __launch_bounds__(256) void proj_v_k(const u16* __restrict__ Wv, const u16* __restrict__ vit,
                                                const u16* __restrict__ bv, u16* __restrict__ vT) {
  int lane = threadIdx.x & 63, wave = threadIdx.x >> 6;
  int l15 = lane & 15, quad = lane >> 4;
  int b = blockIdx.x >> 4;
  int ob = (blockIdx.x >> 2) & 3;
  int js = blockIdx.x & 3;
  int o0 = ob * 64 + wave * 16;
  const u16* arow = Wv + (size_t)(o0 + l15) * 256 + quad * 8;
  short8 af[8];
#pragma unroll
  for (int ks = 0; ks < 8; ks++) af[ks] = *(const short8*)(arow + ks * 32);
  int jt0 = js * 13;
  int jt1 = (jt0 + 13 < 49) ? jt0 + 13 : 49;
  for (int jt = jt0; jt < jt1; jt++) {
    const u16* brow = vit + ((size_t)(b * KW) + jt * 16 + l15) * 256 + quad * 8;
    f32x4 acc = {0.f, 0.f, 0.f, 0.f};
#pragma unroll
    for (int ks = 0; ks < 8; ks++) acc = MFMA16(af[ks], *(const short8*)(brow + ks * 32), acc);
#pragma unroll
    for (int r = 0; r < 4; r++) {
      int o = o0 + quad * 4 + r;
      vT[((size_t)(b * 256) + o) * KW + jt * 16 + l15] = f2bf(acc[r] + bf2f(bv[o]));
    }
  }
}

// ---- fused attention v2: online softmax, barrier-free PV, per-wave LDS P ----
// Grid: blockIdx = pt*16 + h*2 + half; wave w handles b = half*4 + w.
// LDS: bias tile TRANSPOSED [col 784][row 16] (b64 reads) + per-wave P [16][136].
static constexpr int PSTRIDE = 136;
__global__ __launch_bounds__(256, 3) void attn_k(const u16* __restrict__ q, const u16* __restrict__ k,
                                                 const u16* __restrict__ vT, const void* __restrict__ Bb,
                                                 u16* __restrict__ Ob, const int* __restrict__ cnt) {
  int f32m = (*cnt >= 64);
  int tid = threadIdx.x;
  int lane = tid & 63, wave = tid >> 6;
  int l15 = lane & 15, quad = lane >> 4;
  int bid = blockIdx.x;
  int pt = bid >> 4;
  int h = (bid >> 1) & 7;
  int half = bid & 1;
  int b = half * 4 + wave;
  int p0 = pt * 16;
  __shared__ __align__(16) u16 blsT[784 * 16];        // bias transposed [j][p]
  __shared__ __align__(16) u16 Pch[4][16 * PSTRIDE];  // per-wave P, row-major [p][j]

  // cooperative bias tile load (transposed store)
  {
    size_t boff = ((size_t)(h * HW) + p0) * KW;
    if (f32m) {
      const float* bbf = (const float*)Bb + boff;
#pragma unroll
      for (int it = 0; it < 13; it++) {
        int chunk = it * 256 + tid;
        if (chunk < 3136) {
          int row = chunk / 196, c4 = (chunk - row * 196) * 4;
          float4 v = *(const float4*)(bbf + (size_t)row * KW + c4);
          blsT[(c4 + 0) * 16 + row] = f2bf(v.x);
          blsT[(c4 + 1) * 16 + row] = f2bf(v.y);
          blsT[(c4 + 2) * 16 + row] = f2bf(v.z);
          blsT[(c4 + 3) * 16 + row] = f2bf(v.w);
        }
      }
    } else {
      const u16* bbb = (const u16*)Bb + boff;
#pragma unroll
      for (int it = 0; it < 13; it++) {
        int chunk = it * 256 + tid;
        if (chunk < 3136) {
          int row = chunk / 196, c4 = (chunk - row * 196) * 4;
          uint2 lv = *(const uint2*)(bbb + (size_t)row * KW + c4);
          blsT[(c4 + 0) * 16 + row] = (u16)(lv.x & 0xFFFFu);
          blsT[(c4 + 1) * 16 + row] = (u16)(lv.x >> 16);
          blsT[(c4 + 2) * 16 + row] = (u16)(lv.y & 0xFFFFu);
          blsT[(c4 + 3) * 16 + row] = (u16)(lv.y >> 16);
        }
      }
    }
  }
  __syncthreads();  // the ONLY block barrier

  const u16* qp = q + ((size_t)(b * HW) + p0 + l15) * 256 + h * 32 + quad * 8;
  short8 af = *(const short8*)qp;
  const u16* kb = k + (size_t)b * KW * 256 + h * 32 + quad * 8;
  const u16* vb = vT + ((size_t)(b * 256) + h * 32) * KW;
  u16* pw = &Pch[wave][0];

  float m[4], l[4];
  f32x4 oa = {0.f, 0.f, 0.f, 0.f}, oc = {0.f, 0.f, 0.f, 0.f};
#pragma unroll
  for (int r = 0; r < 4; r++) { m[r] = -3.0e38f; l[r] = 0.f; }

#pragma unroll 1
  for (int c = 0; c < 7; c++) {
    f32x4 s[8];
    // QK + bias for 8 j-tiles (tail tiles neutralized to -inf)
#pragma unroll
    for (int t = 0; t < 8; t++) {
      int jt = c * 8 + t;
      int jrow = jt * 16 + l15;
      int jcl = jrow > 783 ? 783 : jrow;
      short8 kf = *(const short8*)(kb + (size_t)jcl * 256);
      f32x4 acc = {0.f, 0.f, 0.f, 0.f};
      acc = MFMA16(af, kf, acc);
      uint2 braw = *(const uint2*)&blsT[jcl * 16 + quad * 4];
      bool valid = jrow < 784;
      s[t][0] = valid ? acc[0] + bflo(braw.x) : -3.0e38f;
      s[t][1] = valid ? acc[1] + bfhi(braw.x) : -3.0e38f;
      s[t][2] = valid ? acc[2] + bflo(braw.y) : -3.0e38f;
      s[t][3] = valid ? acc[3] + bfhi(braw.y) : -3.0e38f;
    }
    // chunk max -> running max, rescale factor
    float cm[4], al[4], ps[4];
#pragma unroll
    for (int r = 0; r < 4; r++) {
      float v = s[0][r];
#pragma unroll
      for (int t = 1; t < 8; t++) v = fmaxf(v, s[t][r]);
      cm[r] = v;
    }
#pragma unroll
    for (int off = 1; off < 16; off <<= 1)
#pragma unroll
      for (int r = 0; r < 4; r++) cm[r] = fmaxf(cm[r], __shfl_xor(cm[r], off));
#pragma unroll
    for (int r = 0; r < 4; r++) {
      float mn = fmaxf(m[r], cm[r]);
      al[r] = __expf(m[r] - mn);
      m[r] = mn;
      ps[r] = 0.f;
    }
    // exp + partial row-sums
#pragma unroll
    for (int t = 0; t < 8; t++)
#pragma unroll
      for (int r = 0; r < 4; r++) {
        float e = __expf(s[t][r] - m[r]);
        s[t][r] = e;
        ps[r] += e;
      }
#pragma unroll
    for (int off = 1; off < 16; off <<= 1)
#pragma unroll
      for (int r = 0; r < 4; r++) ps[r] += __shfl_xor(ps[r], off);
#pragma unroll
    for (int r = 0; r < 4; r++) {
      l[r] = l[r] * al[r] + ps[r];
      oa[r] *= al[r];
      oc[r] *= al[r];
    }
    // P -> per-wave LDS (D-layout write)
#pragma unroll
    for (int t = 0; t < 8; t++) {
      int col = t * 16 + l15;
#pragma unroll
      for (int r = 0; r < 4; r++)
        pw[(quad * 4 + r) * PSTRIDE + col] = f2bf(s[t][r]);
    }
    __builtin_amdgcn_s_waitcnt(0xC07F);  // lgkmcnt(0) only; vmcnt untouched
    // PV: read P in A-layout, V direct from global
#pragma unroll
    for (int kc = 0; kc < 4; kc++) {
      short8 pf = *(const short8*)(pw + l15 * PSTRIDE + kc * 32 + quad * 8);
      int jo = c * 128 + kc * 32 + quad * 8;
      if (jo > 776) jo = 776;  // clamped rows only meet P==0
      short8 v0 = *(const short8*)(vb + (size_t)l15 * KW + jo);
      short8 v1 = *(const short8*)(vb + (size_t)(16 + l15) * KW + jo);
      oa = MFMA16(pf, v0, oa);
      oc = MFMA16(pf, v1, oc);
    }
  }

  size_t obase = ((size_t)(b * HW) + p0 + quad * 4) * 256 + h * 32 + l15;
#pragma unroll
  for (int r = 0; r < 4; r++) {
    float inv = 1.f / l[r];
    Ob[obase + (size_t)r * 256]      = f2bf(oa[r] * inv);
    Ob[obase + (size_t)r * 256 + 16] = f2bf(oc[r] * inv);
  }
}

extern "C" void kernel_launch(void* const* d_in, const int* in_sizes, int n_in,
                              void* d_out, int out_size, void* d_ws, size_t ws_size,
                              hipStream_t stream) {
  (void)in_sizes; (void)n_in; (void)out_size; (void)ws_size;
  const void* x = d_in[0];
  char* ws = (char*)d_ws;
  int* cnt = (int*)(ws + OFF_CNT);
  u16* arena = (u16*)(ws + OFF_W);
  u16* xt  = (u16*)(ws + OFF_XT);
  u16* kit = (u16*)(ws + OFF_KIT);
  u16* vit = (u16*)(ws + OFF_VIT);
  u16* ki  = (u16*)(ws + OFF_KI);   // then k-proj output
  u16* vi  = (u16*)(ws + OFF_VI);   // then vT
  u16* qb  = (u16*)(ws + OFF_Q);
  u16* Obuf = (u16*)(ws + OFF_O);   // overlays xt

  CvtArgs a;
  const int srcidx[12] = {5, 7, 9, 11, 1, 3, 2, 4, 6, 8, 10, 12};
  const int dofs[12] = {AOFF_WQ, AOFF_WK, AOFF_WV, AOFF_WO, AOFF_WKDW, AOFF_WVDW,
                        AOFF_BKDW, AOFF_BVDW, AOFF_BQ, AOFF_BK, AOFF_BV, AOFF_BO};
  const int ns[12] = {65536, 65536, 65536, 65536, 2304, 2304, 256, 256, 256, 256, 256, 256};
  for (int i = 0; i < 12; i++) { a.src[i] = d_in[srcidx[i]]; a.dstoff[i] = dofs[i]; a.n[i] = ns[i]; }

  hipMemsetAsync(d_ws, 0, 8192, stream);  // zero acc + detect counter
  detect_k<<<1, 256, 0, stream>>>((const u32*)x, cnt);
  cvtw_k<<<dim3(32, 12), 256, 0, stream>>>(a, arena, cnt);
  reduce_k<<<1024, 256, 0, stream>>>(x, (double*)d_ws, cnt);
  prep_k<<<1, 256, 0, stream>>>(arena + AOFF_WQ, arena + AOFF_BQ, (float*)d_ws);
  transpose_x_k<<<dim3(98, 8, 8), 256, 0, stream>>>(x, xt, cnt);
  dwconv_k<<<2048, 256, 0, stream>>>(x, arena, ki, vi, cnt);
  transpose_kv_k<<<dim3(25, 8, 16), 256, 0, stream>>>(ki, kit, vi, vit);
  proj2_k<1><<<224, 256, 0, stream>>>(kit, arena + AOFF_WK, nullptr, arena + AOFF_BK,
                                      nullptr, ki, cnt, KW, 7);
  proj_v_k<<<128, 256, 0, stream>>>(arena + AOFF_WV, vit, arena + AOFF_BV, vi);
  proj2_k<0><<<224, 256, 0, stream>>>(xt, arena + AOFF_WQ, (const float*)d_ws, nullptr,
                                      nullptr, qb, cnt, HW, 28);
  attn_k<<<3136, 256, 0, stream>>>(qb, ki, vi, d_in[13], Obuf, cnt);
  proj2_k<2><<<224, 256, 0, stream>>>(Obuf, arena + AOFF_WO, nullptr, arena + AOFF_BO,
                                      x, d_out, cnt, HW, 28);
}